// Round 14
// baseline (6593.320 us; speedup 1.0000x reference)
//
#include <hip/hip_runtime.h>

// Neural ODE RK4, fp32. r12 was LDS-pipe-bound (weights from LDS: 256 b128/
// CU-eval ~3000cy). r13/14: the 128 per-lane weights live in AGPRs - pinned
// by making their only uses `v_accvgpr_read_b32` inline asm ("a" constraint,
// the documented mover). Each read amortized over the wave's 2 rows.
// LDS keeps only uniform x/act broadcasts + stride-5 partial exchange.
// 256 blocks (1/CU) x 512 thr (8 waves = 4 hidden-slices x 2 row-groups).
// (r13 fix: G1Q/G2Q are plain blocks, not do/while - G1ALL juxtaposes them.)

#define NB 1024
#define ND 64
#define NH 256
#define RPB 4
#define NBLK (NB / RPB)   // 256
#define NTHR 512          // 8 waves

// LDS float offsets (tiny now: 4608 fl = 18 KB)
#define XB_OFF 0          // [8 waves][2 rows][64]
#define AB_OFF 1024
#define PART_OFF 2048     // [2][4 rows][64*5] stride-5 conflict-free

#define R64(M) M(0) M(1) M(2) M(3) M(4) M(5) M(6) M(7) M(8) M(9) \
  M(10) M(11) M(12) M(13) M(14) M(15) M(16) M(17) M(18) M(19) \
  M(20) M(21) M(22) M(23) M(24) M(25) M(26) M(27) M(28) M(29) \
  M(30) M(31) M(32) M(33) M(34) M(35) M(36) M(37) M(38) M(39) \
  M(40) M(41) M(42) M(43) M(44) M(45) M(46) M(47) M(48) M(49) \
  M(50) M(51) M(52) M(53) M(54) M(55) M(56) M(57) M(58) M(59) \
  M(60) M(61) M(62) M(63)

#define DW(i) float w1_##i, w2_##i;
#define LW(i) w1_##i = W1[(i) * NH + j]; \
              w2_##i = W2[((hh << 6) + (i)) * ND + l];

// AGPR -> VGPR mover; volatile so it is never CSE'd across evals (which
// would resurrect the 128-live-VGPR pressure problem).
#define ARD(d, s) asm volatile("v_accvgpr_read_b32 %0, %1" : "=v"(d) : "a"(s))

__device__ __forceinline__ float fast_tanh(float x) {
    float e = __expf(2.0f * x);
    float r = __builtin_amdgcn_rcpf(e + 1.0f);
    return 1.0f - 2.0f * r;
}

// lgkmcnt-only barrier: no vmcnt drain (output stores keep flowing).
#define BLOCK_SYNC() do {                                        \
    asm volatile("s_waitcnt lgkmcnt(0)" ::: "memory");           \
    __builtin_amdgcn_s_barrier();                                \
    asm volatile("" ::: "memory");                               \
} while (0)

// GEMM1 step q: 4 AGPR reads feed 8 FMAs (2 rows); x via uniform b128 bcast.
#define G1Q(q, i0, i1, i2, i3) {                                 \
    float4 xa = ((const float4*)xbw)[q];                         \
    float4 xb = ((const float4*)(xbw + ND))[q];                  \
    float t0, t1, t2, t3;                                        \
    ARD(t0, w1_##i0); ARD(t1, w1_##i1);                          \
    ARD(t2, w1_##i2); ARD(t3, w1_##i3);                          \
    h0a = fmaf(t0, xa.x, h0a); h0b = fmaf(t0, xb.x, h0b);        \
    h1a = fmaf(t1, xa.y, h1a); h1b = fmaf(t1, xb.y, h1b);        \
    h0a = fmaf(t2, xa.z, h0a); h0b = fmaf(t2, xb.z, h0b);        \
    h1a = fmaf(t3, xa.w, h1a); h1b = fmaf(t3, xb.w, h1b);        \
}

#define G2Q(q, i0, i1, i2, i3) {                                 \
    float4 va = ((const float4*)abw)[q];                         \
    float4 vb = ((const float4*)(abw + ND))[q];                  \
    float t0, t1, t2, t3;                                        \
    ARD(t0, w2_##i0); ARD(t1, w2_##i1);                          \
    ARD(t2, w2_##i2); ARD(t3, w2_##i3);                          \
    p0a = fmaf(t0, va.x, p0a); p0b = fmaf(t0, vb.x, p0b);        \
    p1a = fmaf(t1, va.y, p1a); p1b = fmaf(t1, vb.y, p1b);        \
    p0a = fmaf(t2, va.z, p0a); p0b = fmaf(t2, vb.z, p0b);        \
    p1a = fmaf(t3, va.w, p1a); p1b = fmaf(t3, vb.w, p1b);        \
}

#define G1ALL() \
  G1Q(0,0,1,2,3)    G1Q(1,4,5,6,7)    G1Q(2,8,9,10,11)   G1Q(3,12,13,14,15) \
  G1Q(4,16,17,18,19) G1Q(5,20,21,22,23) G1Q(6,24,25,26,27) G1Q(7,28,29,30,31) \
  G1Q(8,32,33,34,35) G1Q(9,36,37,38,39) G1Q(10,40,41,42,43) G1Q(11,44,45,46,47) \
  G1Q(12,48,49,50,51) G1Q(13,52,53,54,55) G1Q(14,56,57,58,59) G1Q(15,60,61,62,63)
#define G2ALL() \
  G2Q(0,0,1,2,3)    G2Q(1,4,5,6,7)    G2Q(2,8,9,10,11)   G2Q(3,12,13,14,15) \
  G2Q(4,16,17,18,19) G2Q(5,20,21,22,23) G2Q(6,24,25,26,27) G2Q(7,28,29,30,31) \
  G2Q(8,32,33,34,35) G2Q(9,36,37,38,39) G2Q(10,40,41,42,43) G2Q(11,44,45,46,47) \
  G2Q(12,48,49,50,51) G2Q(13,52,53,54,55) G2Q(14,56,57,58,59) G2Q(15,60,61,62,63)

// One func eval for the wave's 2 rows (elem-per-lane in/out).
#define EVAL(X0, X1, K0, K1) do {                                          \
    xbw[l]      = (X0);                                                    \
    xbw[ND + l] = (X1);                                                    \
    float h0a = b1l, h1a = 0.0f, h0b = b1l, h1b = 0.0f;                    \
    G1ALL()                                                                \
    abw[l]      = fast_tanh(h0a + h1a);                                    \
    abw[ND + l] = fast_tanh(h0b + h1b);                                    \
    float p0a = 0.0f, p1a = 0.0f, p0b = 0.0f, p1b = 0.0f;                  \
    G2ALL()                                                                \
    lds[pob + 0   + l * 5] = p0a + p1a;                                    \
    lds[pob + 320 + l * 5] = p0b + p1b;                                    \
    BLOCK_SYNC();                                                          \
    { int ra = prb + 0   + l * 5;                                          \
      int rb = prb + 320 + l * 5;                                          \
      (K0) = ((lds[ra] + lds[ra+1]) + (lds[ra+2] + lds[ra+3])) + b2l;      \
      (K1) = ((lds[rb] + lds[rb+1]) + (lds[rb+2] + lds[rb+3])) + b2l; }    \
    pob ^= 1280; prb ^= 1280;  /* WAR separated by next eval's barrier */  \
} while (0)

__global__ __launch_bounds__(NTHR)
__attribute__((amdgpu_waves_per_eu(2, 2)))
void node_rk4_kernel(const float* __restrict__ y0,
                     const float* __restrict__ t,
                     const float* W1,      // no restrict: in-loop reload illegal
                     const float* b1,
                     const float* W2,      // no restrict
                     const float* b2,
                     float* __restrict__ out,
                     int nsteps)
{
    __shared__ float lds[PART_OFF + 2560];   // 4608 fl = 18 KB
    const int tid = threadIdx.x;
    const int w   = tid >> 6;        // wave 0..7
    const int l   = tid & 63;        // lane
    const int hh  = w & 3;           // hidden slice
    const int rp  = w >> 2;          // row-group (2 rows each)
    const int j   = (hh << 6) + l;   // owned hidden unit

    // ---- weights -> AGPRs (coalesced one-time loads; only uses are ARD) ----
    R64(DW)
    R64(LW)
    const float b1l = b1[j];
    const float b2l = b2[l];

    float* xbw = lds + XB_OFF + (w << 7);   // wave-private x bcast [2][64]
    float* abw = lds + AB_OFF + (w << 7);   // wave-private act bcast [2][64]

    // part: [pb][row][l*5+hh]; rows = 2rp+{0,1}; stride-5 conflict-free
    int pob = PART_OFF + (2 * rp) * 320 + hh;
    int prb = PART_OFF + (2 * rp) * 320;

    const int row0 = blockIdx.x * RPB + 2 * rp;
    float ya = y0[(row0 + 0) * ND + l];
    float yb = y0[(row0 + 1) * ND + l];
    if (hh == 0) {
        out[(row0 + 0) * ND + l] = ya;
        out[(row0 + 1) * ND + l] = yb;
    }

    for (int s = 0; s < nsteps; ++s) {
        float dt  = t[s + 1] - t[s];
        float dt2 = 0.5f * dt;
        float k1a, k1b, k2a, k2b, k3a, k3b, k4a, k4b;
        EVAL(ya, yb, k1a, k1b);
        EVAL(fmaf(dt2, k1a, ya), fmaf(dt2, k1b, yb), k2a, k2b);
        EVAL(fmaf(dt2, k2a, ya), fmaf(dt2, k2b, yb), k3a, k3b);
        EVAL(fmaf(dt,  k3a, ya), fmaf(dt,  k3b, yb), k4a, k4b);
        float c6 = dt * (1.0f / 6.0f);
        ya = fmaf(c6, (k1a + k4a) + 2.0f * (k2a + k3a), ya);
        yb = fmaf(c6, (k1b + k4b) + 2.0f * (k2b + k3b), yb);
        if (hh == 0) {
            size_t o = (size_t)(s + 1) * (NB * ND);
            out[o + (row0 + 0) * ND + l] = ya;
            out[o + (row0 + 1) * ND + l] = yb;
        }
    }
}

extern "C" void kernel_launch(void* const* d_in, const int* in_sizes, int n_in,
                              void* d_out, int out_size, void* d_ws, size_t ws_size,
                              hipStream_t stream) {
    const float* y0 = (const float*)d_in[0];
    const float* t  = (const float*)d_in[1];
    const float* W1 = (const float*)d_in[2];
    const float* b1 = (const float*)d_in[3];
    const float* W2 = (const float*)d_in[4];
    const float* b2 = (const float*)d_in[5];
    float* out = (float*)d_out;
    int nsteps = in_sizes[1] - 1;
    hipLaunchKernelGGL(node_rk4_kernel, dim3(NBLK), dim3(NTHR), 0, stream,
                       y0, t, W1, b1, W2, b2, out, nsteps);
}

// Round 15
// 5415.150 us; speedup vs baseline: 1.2176x; 1.2176x over previous
//
#include <hip/hip_runtime.h>

// Neural ODE RK4, fp32 — WAVE-SPECIALIZED so no lane holds >64 weights
// (every attempt at 128 weights/lane spilled: RA budget ~88-128 regs).
// G1-waves (w<4): hold W1 column slice in 64 named regs; GEMM1 + tanh + RK4
// integration (redundant per wave, lane = dim). G2-waves (w>=4): hold W2 row
// slice in 64 regs; GEMM2 partials. Handoff via small LDS; 2 barriers/eval.
// 512 blocks x 512 thr = 2 blocks/CU, 4 waves/SIMD (launch_bounds(512,4)
// -> 128-reg budget >= ~100 live). Block owns 2 batch rows.

#define NB 1024
#define ND 64
#define NH 256
#define RPB 2
#define NBLK (NB / RPB)   // 512
#define NTHR 512          // 8 waves: 4x G1 + 4x G2

#define XB_OFF 0          // [4 G1-waves][2 rows][64] private x bcast
#define AB_OFF 512        // [2 rows][256] activations
#define PART_OFF 1024     // [2 rows][64*5] stride-5 partials
#define LDS_FL (PART_OFF + RPB * ND * 5)   // 1664 fl = 6.5 KB

#define R64(M) M(0) M(1) M(2) M(3) M(4) M(5) M(6) M(7) M(8) M(9) \
  M(10) M(11) M(12) M(13) M(14) M(15) M(16) M(17) M(18) M(19) \
  M(20) M(21) M(22) M(23) M(24) M(25) M(26) M(27) M(28) M(29) \
  M(30) M(31) M(32) M(33) M(34) M(35) M(36) M(37) M(38) M(39) \
  M(40) M(41) M(42) M(43) M(44) M(45) M(46) M(47) M(48) M(49) \
  M(50) M(51) M(52) M(53) M(54) M(55) M(56) M(57) M(58) M(59) \
  M(60) M(61) M(62) M(63)

#define Q16(M) M(0,0,1,2,3) M(1,4,5,6,7) M(2,8,9,10,11) M(3,12,13,14,15) \
  M(4,16,17,18,19) M(5,20,21,22,23) M(6,24,25,26,27) M(7,28,29,30,31) \
  M(8,32,33,34,35) M(9,36,37,38,39) M(10,40,41,42,43) M(11,44,45,46,47) \
  M(12,48,49,50,51) M(13,52,53,54,55) M(14,56,57,58,59) M(15,60,61,62,63)

__device__ __forceinline__ float fast_tanh(float x) {
    float e = __expf(2.0f * x);
    float r = __builtin_amdgcn_rcpf(e + 1.0f);
    return 1.0f - 2.0f * r;
}

// lgkmcnt-only barrier: no vmcnt drain (output stores keep flowing).
#define BSYNC() do {                                             \
    asm volatile("s_waitcnt lgkmcnt(0)" ::: "memory");           \
    __builtin_amdgcn_s_barrier();                                \
    asm volatile("" ::: "memory");                               \
} while (0)

// GEMM1 quad: h[j] += W1[i][j]*x[i], 2 rows, 2 chains/row.
#define G1Q(q, i0, i1, i2, i3) {                                 \
    float4 xa_ = xq0[q]; float4 xb_ = xq1[q];                    \
    h0a = fmaf(w1_##i0, xa_.x, h0a); h0b = fmaf(w1_##i0, xb_.x, h0b); \
    h1a = fmaf(w1_##i1, xa_.y, h1a); h1b = fmaf(w1_##i1, xb_.y, h1b); \
    h0a = fmaf(w1_##i2, xa_.z, h0a); h0b = fmaf(w1_##i2, xb_.z, h0b); \
    h1a = fmaf(w1_##i3, xa_.w, h1a); h1b = fmaf(w1_##i3, xb_.w, h1b); \
}

// GEMM2 quad: y[d] += a[jo]*W2[jo][d], 2 rows, 2 chains/row.
#define G2Q(q, i0, i1, i2, i3) {                                 \
    float4 aa_ = aq0[q]; float4 ab_ = aq1[q];                    \
    p00 = fmaf(w2_##i0, aa_.x, p00); p10 = fmaf(w2_##i0, ab_.x, p10); \
    p01 = fmaf(w2_##i1, aa_.y, p01); p11 = fmaf(w2_##i1, ab_.y, p11); \
    p00 = fmaf(w2_##i2, aa_.z, p00); p10 = fmaf(w2_##i2, ab_.z, p10); \
    p01 = fmaf(w2_##i3, aa_.w, p01); p11 = fmaf(w2_##i3, ab_.w, p11); \
}

// One RK4-stage eval from the G1 side: write x, GEMM1, tanh, publish a;
// [B1: G2 computes] [B2]; then read summed partials -> k.
#define G1STAGE(X0, X1, K0, K1) do {                             \
    xbw[l]      = (X0);                                          \
    xbw[ND + l] = (X1);                                          \
    float h0a = b1l, h1a = 0.0f, h0b = b1l, h1b = 0.0f;          \
    Q16(G1Q)                                                     \
    abp[j]      = fast_tanh(h0a + h1a);                          \
    abp[NH + j] = fast_tanh(h0b + h1b);                          \
    BSYNC();  /* B1: a visible to G2 */                          \
    BSYNC();  /* B2: partials visible to G1 */                   \
    { const float* pr = lds + PART_OFF + l * 5;                  \
      (K0) = ((pr[0] + pr[1]) + (pr[2] + pr[3])) + b2l;          \
      pr += 320;                                                 \
      (K1) = ((pr[0] + pr[1]) + (pr[2] + pr[3])) + b2l; }        \
} while (0)

__global__ __launch_bounds__(NTHR, 4)
void node_rk4_kernel(const float* __restrict__ y0,
                     const float* __restrict__ t,
                     const float* W1,      // no restrict: in-loop reload illegal
                     const float* b1,
                     const float* W2,      // no restrict
                     const float* b2,
                     float* __restrict__ out,
                     int nsteps)
{
    __shared__ float lds[LDS_FL];
    const int tid = threadIdx.x;
    const int w   = tid >> 6;        // wave 0..7
    const int l   = tid & 63;        // lane

    if (w < 4) {
        // ================= G1: GEMM1 + tanh + integration =================
        const int j = (w << 6) + l;             // owned hidden unit
        const float b1l = b1[j];
        const float b2l = b2[l];
        #define DW1(i) float w1_##i;
        R64(DW1)
        #define LW1(i) w1_##i = W1[(i) * NH + j];
        R64(LW1)                                 // 64 regs: W1[:, j]

        float* xbw = lds + XB_OFF + (w << 7);   // private [2][64]
        const float4* xq0 = (const float4*)xbw;
        const float4* xq1 = (const float4*)(xbw + ND);
        float* abp = lds + AB_OFF;

        const int row0 = blockIdx.x * RPB;
        float ya = y0[(row0 + 0) * ND + l];
        float yb = y0[(row0 + 1) * ND + l];
        if (w == 0) {
            out[(row0 + 0) * ND + l] = ya;
            out[(row0 + 1) * ND + l] = yb;
        }

        for (int s = 0; s < nsteps; ++s) {
            float dt  = t[s + 1] - t[s];
            float dt2 = 0.5f * dt;
            float k1a, k1b, k2a, k2b, k3a, k3b, k4a, k4b;
            G1STAGE(ya, yb, k1a, k1b);
            G1STAGE(fmaf(dt2, k1a, ya), fmaf(dt2, k1b, yb), k2a, k2b);
            G1STAGE(fmaf(dt2, k2a, ya), fmaf(dt2, k2b, yb), k3a, k3b);
            G1STAGE(fmaf(dt,  k3a, ya), fmaf(dt,  k3b, yb), k4a, k4b);
            float c6 = dt * (1.0f / 6.0f);
            ya = fmaf(c6, (k1a + k4a) + 2.0f * (k2a + k3a), ya);
            yb = fmaf(c6, (k1b + k4b) + 2.0f * (k2b + k3b), yb);
            if (w == 0) {
                size_t o = (size_t)(s + 1) * (NB * ND);
                out[o + (row0 + 0) * ND + l] = ya;
                out[o + (row0 + 1) * ND + l] = yb;
            }
        }
    } else {
        // ================= G2: GEMM2 partials =================
        const int jj = w - 4;                   // j-slice [64jj, 64jj+64)
        #define DW2(i) float w2_##i;
        R64(DW2)
        #define LW2(i) w2_##i = W2[((jj << 6) + (i)) * ND + l];
        R64(LW2)                                 // 64 regs: W2 slice column d=l

        const float4* aq0 = (const float4*)(lds + AB_OFF + (jj << 6));
        const float4* aq1 = (const float4*)(lds + AB_OFF + NH + (jj << 6));
        float* pw = lds + PART_OFF;

        const int niter = 4 * nsteps;
        for (int it = 0; it < niter; ++it) {
            BSYNC();  // B1: wait for activations
            float p00 = 0.0f, p01 = 0.0f, p10 = 0.0f, p11 = 0.0f;
            Q16(G2Q)
            pw[0   + l * 5 + jj] = p00 + p01;   // stride-5: 2-way max (free)
            pw[320 + l * 5 + jj] = p10 + p11;
            BSYNC();  // B2: partials published
        }
    }
}

extern "C" void kernel_launch(void* const* d_in, const int* in_sizes, int n_in,
                              void* d_out, int out_size, void* d_ws, size_t ws_size,
                              hipStream_t stream) {
    const float* y0 = (const float*)d_in[0];
    const float* t  = (const float*)d_in[1];
    const float* W1 = (const float*)d_in[2];
    const float* b1 = (const float*)d_in[3];
    const float* W2 = (const float*)d_in[4];
    const float* b2 = (const float*)d_in[5];
    float* out = (float*)d_out;
    int nsteps = in_sizes[1] - 1;
    hipLaunchKernelGGL(node_rk4_kernel, dim3(NBLK), dim3(NTHR), 0, stream,
                       y0, t, W1, b1, W2, b2, out, nsteps);
}

// Round 16
// 5316.445 us; speedup vs baseline: 1.2402x; 1.0186x over previous
//
#include <hip/hip_runtime.h>

// Neural ODE RK4, fp32 — wave-specialized (r15 structure) + weights loaded
// via `asm volatile global_load_dword` (r16 fix). Mechanism of 6 prior
// failures: compiler marks W1/W2 loads invariant (kernel provably never
// stores through them) -> MachineSink legally sinks them into the loop past
// all "memory" clobbers -> per-eval reloads (FETCH ~740MB, VGPR 56-88).
// Volatile-asm loads cannot be sunk or rematerialized; outputs must stay
// in registers (live ~90 < 128-reg budget of launch_bounds(512,4)).
// G1-waves (w<4): W1 column slice (64 regs) -> GEMM1+tanh+RK4 integration.
// G2-waves (w>=4): W2 row slice (64 regs) -> GEMM2 partials.
// 512 blocks x 512 thr = 2 blocks/CU, 4 waves/SIMD. Block owns 2 batch rows.

#define NB 1024
#define ND 64
#define NH 256
#define RPB 2
#define NBLK (NB / RPB)   // 512
#define NTHR 512          // 8 waves: 4x G1 + 4x G2

#define XB_OFF 0          // [4 G1-waves][2 rows][64] private x bcast
#define AB_OFF 512        // [2 rows][256] activations
#define PART_OFF 1024     // [2 rows][64*5] stride-5 partials
#define LDS_FL (PART_OFF + RPB * ND * 5)   // 1664 fl = 6.5 KB

#define R64(M) M(0) M(1) M(2) M(3) M(4) M(5) M(6) M(7) M(8) M(9) \
  M(10) M(11) M(12) M(13) M(14) M(15) M(16) M(17) M(18) M(19) \
  M(20) M(21) M(22) M(23) M(24) M(25) M(26) M(27) M(28) M(29) \
  M(30) M(31) M(32) M(33) M(34) M(35) M(36) M(37) M(38) M(39) \
  M(40) M(41) M(42) M(43) M(44) M(45) M(46) M(47) M(48) M(49) \
  M(50) M(51) M(52) M(53) M(54) M(55) M(56) M(57) M(58) M(59) \
  M(60) M(61) M(62) M(63)

#define Q16(M) M(0,0,1,2,3) M(1,4,5,6,7) M(2,8,9,10,11) M(3,12,13,14,15) \
  M(4,16,17,18,19) M(5,20,21,22,23) M(6,24,25,26,27) M(7,28,29,30,31) \
  M(8,32,33,34,35) M(9,36,37,38,39) M(10,40,41,42,43) M(11,44,45,46,47) \
  M(12,48,49,50,51) M(13,52,53,54,55) M(14,56,57,58,59) M(15,60,61,62,63)

// 4 un-sinkable loads off one base (offset: immediates), then drain vmcnt.
#define GLD4(d0, d1, d2, d3, BP, S1, S2, S3)                                  \
  asm volatile("global_load_dword %0, %1, off"              : "=v"(d0) : "v"(BP)); \
  asm volatile("global_load_dword %0, %1, off offset:" S1   : "=v"(d1) : "v"(BP)); \
  asm volatile("global_load_dword %0, %1, off offset:" S2   : "=v"(d2) : "v"(BP)); \
  asm volatile("global_load_dword %0, %1, off offset:" S3   : "=v"(d3) : "v"(BP)); \
  asm volatile("s_waitcnt vmcnt(0)" ::: "memory");

__device__ __forceinline__ float fast_tanh(float x) {
    float e = __expf(2.0f * x);
    float r = __builtin_amdgcn_rcpf(e + 1.0f);
    return 1.0f - 2.0f * r;
}

// lgkmcnt-only barrier: no vmcnt drain (output stores keep flowing).
#define BSYNC() do {                                             \
    asm volatile("s_waitcnt lgkmcnt(0)" ::: "memory");           \
    __builtin_amdgcn_s_barrier();                                \
    asm volatile("" ::: "memory");                               \
} while (0)

// GEMM1 quad: h[j] += W1[i][j]*x[i], 2 rows, 2 chains/row.
#define G1Q(q, i0, i1, i2, i3) {                                 \
    float4 xa_ = xq0[q]; float4 xb_ = xq1[q];                    \
    h0a = fmaf(w1_##i0, xa_.x, h0a); h0b = fmaf(w1_##i0, xb_.x, h0b); \
    h1a = fmaf(w1_##i1, xa_.y, h1a); h1b = fmaf(w1_##i1, xb_.y, h1b); \
    h0a = fmaf(w1_##i2, xa_.z, h0a); h0b = fmaf(w1_##i2, xb_.z, h0b); \
    h1a = fmaf(w1_##i3, xa_.w, h1a); h1b = fmaf(w1_##i3, xb_.w, h1b); \
}

// GEMM2 quad: y[d] += a[jo]*W2[jo][d], 2 rows, 2 chains/row.
#define G2Q(q, i0, i1, i2, i3) {                                 \
    float4 aa_ = aq0[q]; float4 ab_ = aq1[q];                    \
    p00 = fmaf(w2_##i0, aa_.x, p00); p10 = fmaf(w2_##i0, ab_.x, p10); \
    p01 = fmaf(w2_##i1, aa_.y, p01); p11 = fmaf(w2_##i1, ab_.y, p11); \
    p00 = fmaf(w2_##i2, aa_.z, p00); p10 = fmaf(w2_##i2, ab_.z, p10); \
    p01 = fmaf(w2_##i3, aa_.w, p01); p11 = fmaf(w2_##i3, ab_.w, p11); \
}

// One RK4-stage eval from the G1 side.
#define G1STAGE(X0, X1, K0, K1) do {                             \
    xbw[l]      = (X0);                                          \
    xbw[ND + l] = (X1);                                          \
    float h0a = b1l, h1a = 0.0f, h0b = b1l, h1b = 0.0f;          \
    Q16(G1Q)                                                     \
    abp[j]      = fast_tanh(h0a + h1a);                          \
    abp[NH + j] = fast_tanh(h0b + h1b);                          \
    BSYNC();  /* B1: a visible to G2 */                          \
    BSYNC();  /* B2: partials visible to G1 */                   \
    { const float* pr = lds + PART_OFF + l * 5;                  \
      (K0) = ((pr[0] + pr[1]) + (pr[2] + pr[3])) + b2l;          \
      pr += 320;                                                 \
      (K1) = ((pr[0] + pr[1]) + (pr[2] + pr[3])) + b2l; }        \
} while (0)

__global__ __launch_bounds__(NTHR, 4)
void node_rk4_kernel(const float* __restrict__ y0,
                     const float* __restrict__ t,
                     const float* __restrict__ W1,
                     const float* __restrict__ b1,
                     const float* __restrict__ W2,
                     const float* __restrict__ b2,
                     float* __restrict__ out,
                     int nsteps)
{
    __shared__ float lds[LDS_FL];
    const int tid = threadIdx.x;
    const int w   = tid >> 6;        // wave 0..7
    const int l   = tid & 63;        // lane

    if (w < 4) {
        // ================= G1: GEMM1 + tanh + integration =================
        const int j = (w << 6) + l;             // owned hidden unit
        const float b1l = b1[j];
        const float b2l = b2[l];
        #define DW1(i) float w1_##i;
        R64(DW1)
        // W1 column j, stride NH*4 = 1024 B -> quad offsets 1024/2048/3072
        #define LW1Q(q, i0, i1, i2, i3) {                        \
            const float* _bp = W1 + (i0) * NH + j;               \
            GLD4(w1_##i0, w1_##i1, w1_##i2, w1_##i3, _bp,        \
                 "1024", "2048", "3072")                         \
        }
        Q16(LW1Q)

        float* xbw = lds + XB_OFF + (w << 7);   // private [2][64]
        const float4* xq0 = (const float4*)xbw;
        const float4* xq1 = (const float4*)(xbw + ND);
        float* abp = lds + AB_OFF;

        const int row0 = blockIdx.x * RPB;
        float ya = y0[(row0 + 0) * ND + l];
        float yb = y0[(row0 + 1) * ND + l];
        if (w == 0) {
            out[(row0 + 0) * ND + l] = ya;
            out[(row0 + 1) * ND + l] = yb;
        }

        for (int s = 0; s < nsteps; ++s) {
            float dt  = t[s + 1] - t[s];
            float dt2 = 0.5f * dt;
            float k1a, k1b, k2a, k2b, k3a, k3b, k4a, k4b;
            G1STAGE(ya, yb, k1a, k1b);
            G1STAGE(fmaf(dt2, k1a, ya), fmaf(dt2, k1b, yb), k2a, k2b);
            G1STAGE(fmaf(dt2, k2a, ya), fmaf(dt2, k2b, yb), k3a, k3b);
            G1STAGE(fmaf(dt,  k3a, ya), fmaf(dt,  k3b, yb), k4a, k4b);
            float c6 = dt * (1.0f / 6.0f);
            ya = fmaf(c6, (k1a + k4a) + 2.0f * (k2a + k3a), ya);
            yb = fmaf(c6, (k1b + k4b) + 2.0f * (k2b + k3b), yb);
            if (w == 0) {
                size_t o = (size_t)(s + 1) * (NB * ND);
                out[o + (row0 + 0) * ND + l] = ya;
                out[o + (row0 + 1) * ND + l] = yb;
            }
        }
    } else {
        // ================= G2: GEMM2 partials =================
        const int jj = w - 4;                   // j-slice [64jj, 64jj+64)
        #define DW2(i) float w2_##i;
        R64(DW2)
        // W2 rows jj*64+i, column l; stride ND*4 = 256 B -> offsets 256/512/768
        #define LW2Q(q, i0, i1, i2, i3) {                        \
            const float* _bp = W2 + ((jj << 6) + (i0)) * ND + l; \
            GLD4(w2_##i0, w2_##i1, w2_##i2, w2_##i3, _bp,        \
                 "256", "512", "768")                            \
        }
        Q16(LW2Q)

        const float4* aq0 = (const float4*)(lds + AB_OFF + (jj << 6));
        const float4* aq1 = (const float4*)(lds + AB_OFF + NH + (jj << 6));
        float* pw = lds + PART_OFF;

        const int niter = 4 * nsteps;
        for (int it = 0; it < niter; ++it) {
            BSYNC();  // B1: wait for activations
            float p00 = 0.0f, p01 = 0.0f, p10 = 0.0f, p11 = 0.0f;
            Q16(G2Q)
            pw[0   + l * 5 + jj] = p00 + p01;   // stride-5: 2-way max (free)
            pw[320 + l * 5 + jj] = p10 + p11;
            BSYNC();  // B2: partials published
        }
    }
}

extern "C" void kernel_launch(void* const* d_in, const int* in_sizes, int n_in,
                              void* d_out, int out_size, void* d_ws, size_t ws_size,
                              hipStream_t stream) {
    const float* y0 = (const float*)d_in[0];
    const float* t  = (const float*)d_in[1];
    const float* W1 = (const float*)d_in[2];
    const float* b1 = (const float*)d_in[3];
    const float* W2 = (const float*)d_in[4];
    const float* b2 = (const float*)d_in[5];
    float* out = (float*)d_out;
    int nsteps = in_sizes[1] - 1;
    hipLaunchKernelGGL(node_rk4_kernel, dim3(NBLK), dim3(NTHR), 0, stream,
                       y0, t, W1, b1, W2, b2, out, nsteps);
}